// Round 13
// baseline (353.203 us; speedup 1.0000x reference)
//
#include <hip/hip_runtime.h>
#include <math.h>

#define NN 262144
#define DD 128
#define EPS_SL 1e-8f
#define EPS_LN 1e-5f
#define THREADS 512
#define TILE_M 64
#define NBLOCKS 256
#define NTILES (NN / TILE_M)          // 4096
#define TPB (NTILES / NBLOCKS)        // 16

typedef __attribute__((ext_vector_type(8))) short bf16x8;
typedef __attribute__((ext_vector_type(4))) float f32x4;

// LDS layout (bytes). Subtiled MFMA-native [kb][row][8] bf16; X XOR-swizzled.
// W regions used only in the prologue (weights live in registers after), but
// the 158KB footprint pins occupancy to 8 waves/CU, matching waves_per_eu(2).
#define OFF_W1 0                       // [36][128][8] bf16 = 73728 B  (K=288 pad)
#define OFF_W2 73728                   // [16][128][8] bf16 = 32768 B
#define OFF_X  106496                  // [36][64][8]  bf16 = 36864 B
#define OFF_H  143360                  // [16][64][8]  bf16 = 16384 B
#define OFF_RED 159744                 // 256 float2   =  2048 B
#define SMEM_TOT 161792

// d_ws layout (CSR build)
#define WS_OFFS   0                    // (NN+1) int
#define WS_CURSOR 1048832              // NN int
#define WS_BSUM   2097408              // 1024 int
#define WS_ESRC   2101504              // E int

__device__ inline unsigned short f2bf(float f) {
    union { float f; unsigned int i; } v; v.f = f;
    unsigned int r = v.i + 0x7fffu + ((v.i >> 16) & 1u);
    return (unsigned short)(r >> 16);
}
__device__ inline unsigned int pack2(float a, float b) {
    return (unsigned int)f2bf(a) | ((unsigned int)f2bf(b) << 16);
}
__device__ inline uint4 pack8(float4 a, float4 b) {
    return make_uint4(pack2(a.x, a.y), pack2(a.z, a.w),
                      pack2(b.x, b.y), pack2(b.z, b.w));
}
__device__ inline float signed_log(float x) {
    float l = __logf(fabsf(x) + EPS_SL);
    return (x > 0.f) ? l : ((x < 0.f) ? -l : 0.f);
}
// swizzled X store/load: unit index (kb*64+row) ^ (kb&7)
__device__ inline void stx(unsigned short* sX, int kb, int row, uint4 v) {
    *(uint4*)(sX + (((kb * 64 + row) ^ (kb & 7)) * 8)) = v;
}
__device__ inline bf16x8 ldx(const unsigned short* sX, int kb, int row) {
    return *(const bf16x8*)(sX + (((kb * 64 + row) ^ (kb & 7)) * 8));
}

// LDS-only block barrier (no vmcnt drain; r10-proven neutral)
__device__ inline void block_sync_lds() {
    __builtin_amdgcn_sched_barrier(0);
    asm volatile("s_waitcnt lgkmcnt(0)" ::: "memory");
    __builtin_amdgcn_s_barrier();
    __builtin_amdgcn_sched_barrier(0);
}

// ---------------- CSR build ----------------
__global__ void hist_kernel(const int* __restrict__ dst, int* counts, int E) {
    int e = blockIdx.x * blockDim.x + threadIdx.x;
    if (e < E) atomicAdd(&counts[dst[e]], 1);
}

__global__ void scan_local(int* offs, int* bsum) {
    __shared__ int tmp[256];
    int t = threadIdx.x, i = blockIdx.x * 256 + t;
    int own = offs[i];
    tmp[t] = own;
    __syncthreads();
    for (int off = 1; off < 256; off <<= 1) {
        int v = (t >= off) ? tmp[t - off] : 0;
        __syncthreads();
        tmp[t] += v;
        __syncthreads();
    }
    offs[i] = tmp[t] - own;
    if (t == 255) bsum[blockIdx.x] = tmp[255];
}

__global__ void scan_bsum(int* bsum) {
    __shared__ int tmp[1024];
    int t = threadIdx.x;
    int own = bsum[t];
    tmp[t] = own;
    __syncthreads();
    for (int off = 1; off < 1024; off <<= 1) {
        int v = (t >= off) ? tmp[t - off] : 0;
        __syncthreads();
        tmp[t] += v;
        __syncthreads();
    }
    bsum[t] = tmp[t] - own;
}

__global__ void scan_fixup(int* offs, const int* __restrict__ bsum, int* cursor, int E) {
    int i = blockIdx.x * 256 + threadIdx.x;
    int v = offs[i] + bsum[i >> 8];
    offs[i] = v;
    cursor[i] = v;
    if (i == 0) offs[NN] = E;
}

__global__ void fill_kernel(const int* __restrict__ src, const int* __restrict__ dst,
                            int* cursor, int* esrc, int E) {
    int e = blockIdx.x * blockDim.x + threadIdx.x;
    if (e < E) {
        int p = atomicAdd(&cursor[dst[e]], 1);
        esrc[p] = src[e];
    }
}

// ---------------- CSR gather -> upstream bf16 (one row per 512B out slot) ----
__global__ __launch_bounds__(256) void gather_kernel(
    const float4* __restrict__ h4, const int* __restrict__ offs,
    const int* __restrict__ esrc, char* outb)
{
    int stride = gridDim.x * 256;
    for (int idx = blockIdx.x * 256 + threadIdx.x; idx < NN * 16; idx += stride) {
        int n = idx >> 4, c = idx & 15;
        int o0 = offs[n], o1 = offs[n + 1];
        float4 a = make_float4(0.f, 0.f, 0.f, 0.f);
        float4 b = make_float4(0.f, 0.f, 0.f, 0.f);
        for (int e = o0; e < o1; ++e) {
            const float4* hr = h4 + (size_t)esrc[e] * 32 + c * 2;
            float4 p0 = hr[0], p1 = hr[1];
            a.x += p0.x; a.y += p0.y; a.z += p0.z; a.w += p0.w;
            b.x += p1.x; b.y += p1.y; b.z += p1.z; b.w += p1.w;
        }
        *(uint4*)(outb + (size_t)n * 512 + c * 16) = pack8(a, b);
    }
}

// ---------------- fallback atomic scatter ----------------
__global__ void scatter_kernel(const float4* __restrict__ h4,
                               const int* __restrict__ src,
                               const int* __restrict__ dst,
                               float* up, int E) {
    int tid = blockIdx.x * blockDim.x + threadIdx.x;
    int e = tid >> 5;
    if (e >= E) return;
    int c = tid & 31;
    float4 v = h4[(size_t)src[e] * 32 + c];
    float* o = up + (size_t)dst[e] * DD + c * 4;
    atomicAdd(o + 0, v.x);
    atomicAdd(o + 1, v.y);
    atomicAdd(o + 2, v.z);
    atomicAdd(o + 3, v.w);
}

// GEMM steps over named register fragments
#define G1(ks, Wc0, Wc1) do { \
    const int kb_ = (ks) * 4 + lk; \
    bf16x8 a0_ = ldx(sX, kb_, wm * 32 + l15); \
    bf16x8 a1_ = ldx(sX, kb_, wm * 32 + 16 + l15); \
    acc[0][0] = __builtin_amdgcn_mfma_f32_16x16x32_bf16(a0_, Wc0, acc[0][0], 0, 0, 0); \
    acc[0][1] = __builtin_amdgcn_mfma_f32_16x16x32_bf16(a0_, Wc1, acc[0][1], 0, 0, 0); \
    acc[1][0] = __builtin_amdgcn_mfma_f32_16x16x32_bf16(a1_, Wc0, acc[1][0], 0, 0, 0); \
    acc[1][1] = __builtin_amdgcn_mfma_f32_16x16x32_bf16(a1_, Wc1, acc[1][1], 0, 0, 0); \
} while (0)

#define G2(ks, Wc0, Wc1) do { \
    const int kb_ = (ks) * 4 + lk; \
    bf16x8 a0_ = *(const bf16x8*)(sH + (kb_ * 64 + wm * 32 + l15) * 8); \
    bf16x8 a1_ = *(const bf16x8*)(sH + (kb_ * 64 + wm * 32 + 16 + l15) * 8); \
    acc2[0][0] = __builtin_amdgcn_mfma_f32_16x16x32_bf16(a0_, Wc0, acc2[0][0], 0, 0, 0); \
    acc2[0][1] = __builtin_amdgcn_mfma_f32_16x16x32_bf16(a0_, Wc1, acc2[0][1], 0, 0, 0); \
    acc2[1][0] = __builtin_amdgcn_mfma_f32_16x16x32_bf16(a1_, Wc0, acc2[1][0], 0, 0, 0); \
    acc2[1][1] = __builtin_amdgcn_mfma_f32_16x16x32_bf16(a1_, Wc1, acc2[1][1], 0, 0, 0); \
} while (0)

// ---------------- pipelined MFMA node MLP + LayerNorm (reg weights) --------
// amdgpu_waves_per_eu(2,2): allow the allocator the full 2-waves/EU register
// budget (~256 VGPR) — LDS already caps occupancy at 8 waves/CU, so no loss.
template <int GATHER>
__global__ __launch_bounds__(THREADS)
__attribute__((amdgpu_waves_per_eu(2, 2)))
void node_kernel(
    const float* __restrict__ h, const void* up,
    const float* __restrict__ c1, const float* __restrict__ c2,
    const float* __restrict__ c3, const float* __restrict__ c4,
    const float* __restrict__ qn,
    const float* __restrict__ W1, const float* __restrict__ b1,
    const float* __restrict__ W2, const float* __restrict__ b2,
    const float* __restrict__ gamma, const float* __restrict__ beta,
    float* out)
{
    extern __shared__ char smem[];
    unsigned short* sW1 = (unsigned short*)(smem + OFF_W1);
    unsigned short* sW2 = (unsigned short*)(smem + OFF_W2);
    unsigned short* sX  = (unsigned short*)(smem + OFF_X);
    unsigned short* sH  = (unsigned short*)(smem + OFF_H);
    float2* red = (float2*)(smem + OFF_RED);

    const int tid = threadIdx.x;

    // ---- stage transposed bf16 weights once per block (prologue only) ----
    for (int c = tid; c < 36 * 128; c += THREADS) {
        int kb = c >> 7, n = c & 127;
        unsigned short tmp[8] __attribute__((aligned(16)));
        #pragma unroll
        for (int j = 0; j < 8; ++j) {
            int k = kb * 8 + j;
            tmp[j] = (k < 261) ? f2bf(W1[k * DD + n]) : (unsigned short)0;
        }
        *(uint4*)(sW1 + c * 8) = *(const uint4*)tmp;
    }
    for (int c = tid; c < 16 * 128; c += THREADS) {
        int kb = c >> 7, n = c & 127;
        unsigned short tmp[8] __attribute__((aligned(16)));
        #pragma unroll
        for (int j = 0; j < 8; ++j) tmp[j] = f2bf(W2[(kb * 8 + j) * DD + n]);
        *(uint4*)(sW2 + c * 8) = *(const uint4*)tmp;
    }
    // zero pad rows kb 33..35 once (never overwritten)
    if (tid < 192) {
        int kb = 33 + (tid >> 6), row = tid & 63;
        stx(sX, kb, row, make_uint4(0u, 0u, 0u, 0u));
    }

    const int lane = tid & 63;
    const int w    = tid >> 6;
    const int wm   = w >> 2;
    const int wn   = w & 3;
    const int l15  = lane & 15;
    const int lk   = lane >> 4;
    const int col0 = wn * 32 + l15;
    const int col1 = col0 + 16;

    __syncthreads();   // weights staged

    // ---- hoist weight fragments into NAMED registers (104 VGPR) ----
    const bf16x8* W1f = (const bf16x8*)sW1;
    const bf16x8* W2f = (const bf16x8*)sW2;
    bf16x8 w1_0a = W1f[(0*4+lk)*128 + col0], w1_0b = W1f[(0*4+lk)*128 + col1];
    bf16x8 w1_1a = W1f[(1*4+lk)*128 + col0], w1_1b = W1f[(1*4+lk)*128 + col1];
    bf16x8 w1_2a = W1f[(2*4+lk)*128 + col0], w1_2b = W1f[(2*4+lk)*128 + col1];
    bf16x8 w1_3a = W1f[(3*4+lk)*128 + col0], w1_3b = W1f[(3*4+lk)*128 + col1];
    bf16x8 w1_4a = W1f[(4*4+lk)*128 + col0], w1_4b = W1f[(4*4+lk)*128 + col1];
    bf16x8 w1_5a = W1f[(5*4+lk)*128 + col0], w1_5b = W1f[(5*4+lk)*128 + col1];
    bf16x8 w1_6a = W1f[(6*4+lk)*128 + col0], w1_6b = W1f[(6*4+lk)*128 + col1];
    bf16x8 w1_7a = W1f[(7*4+lk)*128 + col0], w1_7b = W1f[(7*4+lk)*128 + col1];
    bf16x8 w1_8a = W1f[(8*4+lk)*128 + col0], w1_8b = W1f[(8*4+lk)*128 + col1];
    bf16x8 w2_0a = W2f[(0*4+lk)*128 + col0], w2_0b = W2f[(0*4+lk)*128 + col1];
    bf16x8 w2_1a = W2f[(1*4+lk)*128 + col0], w2_1b = W2f[(1*4+lk)*128 + col1];
    bf16x8 w2_2a = W2f[(2*4+lk)*128 + col0], w2_2b = W2f[(2*4+lk)*128 + col1];
    bf16x8 w2_3a = W2f[(3*4+lk)*128 + col0], w2_3b = W2f[(3*4+lk)*128 + col1];

    const float b1v[2] = {b1[col0], b1[col1]};
    const float b2v[2] = {b2[col0], b2[col1]};
    const float gv[2]  = {gamma[col0], gamma[col1]};
    const float bv[2]  = {beta[col0], beta[col1]};

    // chunk coords (loop-invariant): thread owns (k0, r0) and (k0, r0+32)
    const int k0 = tid & 15;
    const int r0 = tid >> 4;          // 0..31

    // prefetch registers
    float4 h0a, h0b, h1a, h1b;
    uint4  u0, u1;                    // GATHER=1
    float4 v0a, v0b, v1a, v1b;        // GATHER=0
    float pc1 = 0.f, pc2 = 0.f, pc3 = 0.f, pc4 = 0.f, pc5 = 0.f;

    // ---- prologue prefetch: tile 0 ----
    {
        int base = blockIdx.x * TPB * TILE_M;
        const float* hp = h + (size_t)(base + r0) * DD + k0 * 8;
        h0a = *(const float4*)hp;       h0b = *(const float4*)(hp + 4);
        h1a = *(const float4*)(hp + 32 * DD); h1b = *(const float4*)(hp + 32 * DD + 4);
        if (GATHER) {
            const char* ub = (const char*)up;
            u0 = *(const uint4*)(ub + (size_t)(base + r0) * 512 + k0 * 16);
            u1 = *(const uint4*)(ub + (size_t)(base + r0 + 32) * 512 + k0 * 16);
        } else {
            const float* uf = (const float*)up + (size_t)(base + r0) * DD + k0 * 8;
            v0a = *(const float4*)uf;       v0b = *(const float4*)(uf + 4);
            v1a = *(const float4*)(uf + 32 * DD); v1b = *(const float4*)(uf + 32 * DD + 4);
        }
        if (tid < 64) {
            int n0 = base + tid;
            pc1 = c1[n0]; pc2 = c2[n0]; pc3 = c3[n0]; pc4 = c4[n0]; pc5 = qn[n0];
        }
    }
    __syncthreads();

    for (int tt = 0; tt < TPB; ++tt) {
        const int base = (blockIdx.x * TPB + tt) * TILE_M;

        // ---- write prefetched regs -> sX ----
        stx(sX, k0, r0,      pack8(h0a, h0b));
        stx(sX, k0, r0 + 32, pack8(h1a, h1b));
        if (GATHER) {
            stx(sX, 16 + k0, r0,      u0);
            stx(sX, 16 + k0, r0 + 32, u1);
        } else {
            stx(sX, 16 + k0, r0,      pack8(v0a, v0b));
            stx(sX, 16 + k0, r0 + 32, pack8(v1a, v1b));
        }
        if (tid < 64) {
            uint4 pv = make_uint4(pack2(signed_log(pc1), signed_log(pc2)),
                                  pack2(signed_log(pc3), signed_log(pc4)),
                                  pack2(signed_log(pc5), 0.f), 0u);
            stx(sX, 32, tid, pv);
        }

        // ---- issue prefetch for next tile (overlaps GEMM + epilogue) ----
        if (tt + 1 < TPB) {
            int bn = base + TILE_M;
            const float* hp = h + (size_t)(bn + r0) * DD + k0 * 8;
            h0a = *(const float4*)hp;       h0b = *(const float4*)(hp + 4);
            h1a = *(const float4*)(hp + 32 * DD); h1b = *(const float4*)(hp + 32 * DD + 4);
            if (GATHER) {
                const char* ub = (const char*)up;
                u0 = *(const uint4*)(ub + (size_t)(bn + r0) * 512 + k0 * 16);
                u1 = *(const uint4*)(ub + (size_t)(bn + r0 + 32) * 512 + k0 * 16);
            } else {
                const float* uf = (const float*)up + (size_t)(bn + r0) * DD + k0 * 8;
                v0a = *(const float4*)uf;       v0b = *(const float4*)(uf + 4);
                v1a = *(const float4*)(uf + 32 * DD); v1b = *(const float4*)(uf + 32 * DD + 4);
            }
            if (tid < 64) {
                int n0 = bn + tid;
                pc1 = c1[n0]; pc2 = c2[n0]; pc3 = c3[n0]; pc4 = c4[n0]; pc5 = qn[n0];
            }
        }
        block_sync_lds();   // B1: sX ready

        // ---- GEMM1: (64x288) @ (288x128); B operands in registers ----
        f32x4 acc[2][2] = {};
        G1(0, w1_0a, w1_0b);
        G1(1, w1_1a, w1_1b);
        G1(2, w1_2a, w1_2b);
        G1(3, w1_3a, w1_3b);
        G1(4, w1_4a, w1_4b);
        G1(5, w1_5a, w1_5b);
        G1(6, w1_6a, w1_6b);
        G1(7, w1_7a, w1_7b);
        G1(8, w1_8a, w1_8b);

        // silu -> hid tile
        #pragma unroll
        for (int fm = 0; fm < 2; ++fm) {
            int row = wm * 32 + fm * 16 + lk * 4;
            #pragma unroll
            for (int fn = 0; fn < 2; ++fn) {
                int col = wn * 32 + fn * 16 + l15;
                int kbh = col >> 3, ko = col & 7;
                #pragma unroll
                for (int r = 0; r < 4; ++r) {
                    float v = acc[fm][fn][r] + b1v[fn];
                    float sg = 1.f / (1.f + __expf(-v));
                    sH[(kbh * 64 + row + r) * 8 + ko] = f2bf(v * sg);
                }
            }
        }
        block_sync_lds();   // B2: sH ready

        // ---- GEMM2: (64x128) @ (128x128); B operands in registers ----
        f32x4 acc2[2][2] = {};
        G2(0, w2_0a, w2_0b);
        G2(1, w2_1a, w2_1b);
        G2(2, w2_2a, w2_2b);
        G2(3, w2_3a, w2_3b);

        // ---- residual + LN partials ----
        float rs1[2][4], rs2[2][4];
        #pragma unroll
        for (int fm = 0; fm < 2; ++fm) {
            #pragma unroll
            for (int r = 0; r < 4; ++r) {
                size_t rowg = (size_t)(base + wm * 32 + fm * 16 + lk * 4 + r) * DD;
                float z0 = acc2[fm][0][r] + b2v[0] + h[rowg + col0];
                float z1 = acc2[fm][1][r] + b2v[1] + h[rowg + col1];
                acc2[fm][0][r] = z0; acc2[fm][1][r] = z1;
                float s = z0 + z1, q = z0 * z0 + z1 * z1;
                #pragma unroll
                for (int off = 1; off < 16; off <<= 1) {
                    s += __shfl_xor(s, off);
                    q += __shfl_xor(q, off);
                }
                rs1[fm][r] = s; rs2[fm][r] = q;
            }
        }
        if (l15 == 0) {
            #pragma unroll
            for (int fm = 0; fm < 2; ++fm)
                #pragma unroll
                for (int r = 0; r < 4; ++r)
                    red[wn * 64 + wm * 32 + fm * 16 + lk * 4 + r] =
                        make_float2(rs1[fm][r], rs2[fm][r]);
        }
        block_sync_lds();   // B3: red ready

        #pragma unroll
        for (int fm = 0; fm < 2; ++fm) {
            #pragma unroll
            for (int r = 0; r < 4; ++r) {
                int rloc = wm * 32 + fm * 16 + lk * 4 + r;
                float2 t0 = red[rloc], t1 = red[64 + rloc],
                       t2 = red[128 + rloc], t3 = red[192 + rloc];
                float S = t0.x + t1.x + t2.x + t3.x;
                float Q = t0.y + t1.y + t2.y + t3.y;
                float mean = S * (1.f / 128.f);
                float var  = Q * (1.f / 128.f) - mean * mean;
                float rstd = rsqrtf(var + EPS_LN);
                size_t rowg = (size_t)(base + rloc) * DD;
                out[rowg + col0] = (acc2[fm][0][r] - mean) * rstd * gv[0] + bv[0];
                out[rowg + col1] = (acc2[fm][1][r] - mean) * rstd * gv[1] + bv[1];
            }
        }
        // loop back: sX rewrite is 2+ barriers after last sX read -> safe
    }
}

extern "C" void kernel_launch(void* const* d_in, const int* in_sizes, int n_in,
                              void* d_out, int out_size, void* d_ws, size_t ws_size,
                              hipStream_t stream) {
    const float* h     = (const float*)d_in[0];
    const float* c1    = (const float*)d_in[1];
    const float* c2    = (const float*)d_in[2];
    const float* c3    = (const float*)d_in[3];
    const float* c4    = (const float*)d_in[4];
    const float* qn    = (const float*)d_in[5];
    const int*   src   = (const int*)d_in[6];
    const int*   dst   = (const int*)d_in[7];
    const float* W1    = (const float*)d_in[8];
    const float* b1    = (const float*)d_in[9];
    const float* W2    = (const float*)d_in[10];
    const float* b2    = (const float*)d_in[11];
    const float* gamma = (const float*)d_in[12];
    const float* beta  = (const float*)d_in[13];
    float* out = (float*)d_out;
    int E = in_sizes[6];
    size_t ws_needed = (size_t)WS_ESRC + (size_t)E * 4;

    if (ws_size >= ws_needed) {
        char* ws = (char*)d_ws;
        int* offs   = (int*)(ws + WS_OFFS);
        int* cursor = (int*)(ws + WS_CURSOR);
        int* bsum   = (int*)(ws + WS_BSUM);
        int* esrc   = (int*)(ws + WS_ESRC);

        hipMemsetAsync(offs, 0, (size_t)NN * sizeof(int), stream);
        int eb = (E + 255) / 256;
        hist_kernel<<<eb, 256, 0, stream>>>(dst, offs, E);
        scan_local<<<NN / 256, 256, 0, stream>>>(offs, bsum);
        scan_bsum<<<1, 1024, 0, stream>>>(bsum);
        scan_fixup<<<NN / 256, 256, 0, stream>>>(offs, bsum, cursor, E);
        fill_kernel<<<eb, 256, 0, stream>>>(src, dst, cursor, esrc, E);

        gather_kernel<<<2048, 256, 0, stream>>>((const float4*)h, offs, esrc, (char*)d_out);

        hipFuncSetAttribute(reinterpret_cast<const void*>(&node_kernel<1>),
                            hipFuncAttributeMaxDynamicSharedMemorySize, SMEM_TOT);
        node_kernel<1><<<NBLOCKS, THREADS, SMEM_TOT, stream>>>(
            h, d_out, c1, c2, c3, c4, qn,
            W1, b1, W2, b2, gamma, beta, out);
    } else {
        // fallback: atomic scatter into d_out (fp32 upstream)
        hipMemsetAsync(d_out, 0, (size_t)NN * DD * sizeof(float), stream);
        int sthreads = E * 32;
        int sblocks = (sthreads + 255) / 256;
        scatter_kernel<<<sblocks, 256, 0, stream>>>((const float4*)h, src, dst, out, E);
        hipFuncSetAttribute(reinterpret_cast<const void*>(&node_kernel<0>),
                            hipFuncAttributeMaxDynamicSharedMemorySize, SMEM_TOT);
        node_kernel<0><<<NBLOCKS, THREADS, SMEM_TOT, stream>>>(
            h, d_out, c1, c2, c3, c4, qn,
            W1, b1, W2, b2, gamma, beta, out);
    }
}

// Round 14
// 261.171 us; speedup vs baseline: 1.3524x; 1.3524x over previous
//
#include <hip/hip_runtime.h>
#include <math.h>

#define NN 262144
#define DD 128
#define EPS_SL 1e-8f
#define EPS_LN 1e-5f
#define THREADS 512
#define NBLOCKS 256

typedef __attribute__((ext_vector_type(8))) short bf16x8;
typedef __attribute__((ext_vector_type(4))) float f32x4;

// fast-path LDS
#define OFF_W1  0                      // [36][128][8] bf16 = 73728 (k-permuted [up|h|phys])
#define OFF_W2  73728                  // [16][128][8] bf16 = 32768
#define OFF_B   106496                 // b1|b2|gamma|beta 4*128 f32 = 2048
#define OFF_HID 108544                 // 8 waves * 4096 B = 32768
#define SMEM_TOT 141312

// fallback LDS (r4-proven)
#define FB_OFF_W1 0
#define FB_OFF_W2 73728
#define FB_OFF_X  106496
#define FB_OFF_H  143360
#define FB_OFF_RED 159744
#define FB_SMEM_TOT 161792

// d_ws layout (CSR build)
#define WS_OFFS   0                    // (NN+1) int
#define WS_CURSOR 1048832              // NN int
#define WS_BSUM   2097408              // 1024 int
#define WS_ESRC   2101504              // E int

__device__ inline unsigned short f2bf(float f) {
    union { float f; unsigned int i; } v; v.f = f;
    unsigned int r = v.i + 0x7fffu + ((v.i >> 16) & 1u);
    return (unsigned short)(r >> 16);
}
__device__ inline float bf2f(unsigned short u) {
    union { float f; unsigned int i; } v; v.i = ((unsigned int)u) << 16; return v.f;
}
__device__ inline unsigned int pack2(float a, float b) {
    return (unsigned int)f2bf(a) | ((unsigned int)f2bf(b) << 16);
}
__device__ inline uint4 pack8(float4 a, float4 b) {
    return make_uint4(pack2(a.x, a.y), pack2(a.z, a.w),
                      pack2(b.x, b.y), pack2(b.z, b.w));
}
__device__ inline float signed_log(float x) {
    float l = __logf(fabsf(x) + EPS_SL);
    return (x > 0.f) ? l : ((x < 0.f) ? -l : 0.f);
}
// 64-row swizzled X helpers (fallback kernel)
__device__ inline void stx64(unsigned short* sX, int kb, int row, uint4 v) {
    *(uint4*)(sX + (((kb * 64 + row) ^ (kb & 7)) * 8)) = v;
}
__device__ inline bf16x8 ldx64(const unsigned short* sX, int kb, int row) {
    return *(const bf16x8*)(sX + (((kb * 64 + row) ^ (kb & 7)) * 8));
}

// ---------------- CSR build ----------------
__global__ void hist_kernel(const int* __restrict__ dst, int* counts, int E) {
    int e = blockIdx.x * blockDim.x + threadIdx.x;
    if (e < E) atomicAdd(&counts[dst[e]], 1);
}

__global__ void scan_local(int* offs, int* bsum) {
    __shared__ int tmp[256];
    int t = threadIdx.x, i = blockIdx.x * 256 + t;
    int own = offs[i];
    tmp[t] = own;
    __syncthreads();
    for (int off = 1; off < 256; off <<= 1) {
        int v = (t >= off) ? tmp[t - off] : 0;
        __syncthreads();
        tmp[t] += v;
        __syncthreads();
    }
    offs[i] = tmp[t] - own;
    if (t == 255) bsum[blockIdx.x] = tmp[255];
}

__global__ void scan_bsum(int* bsum) {
    __shared__ int tmp[1024];
    int t = threadIdx.x;
    int own = bsum[t];
    tmp[t] = own;
    __syncthreads();
    for (int off = 1; off < 1024; off <<= 1) {
        int v = (t >= off) ? tmp[t - off] : 0;
        __syncthreads();
        tmp[t] += v;
        __syncthreads();
    }
    bsum[t] = tmp[t] - own;
}

__global__ void scan_fixup(int* offs, const int* __restrict__ bsum, int* cursor, int E) {
    int i = blockIdx.x * 256 + threadIdx.x;
    int v = offs[i] + bsum[i >> 8];
    offs[i] = v;
    cursor[i] = v;
    if (i == 0) offs[NN] = E;
}

__global__ void fill_kernel(const int* __restrict__ src, const int* __restrict__ dst,
                            int* cursor, int* esrc, int E) {
    int e = blockIdx.x * blockDim.x + threadIdx.x;
    if (e < E) {
        int p = atomicAdd(&cursor[dst[e]], 1);
        esrc[p] = src[e];
    }
}

// ---- CSR gather -> unified bf16 slot per node: [up(256B) | h(256B)] ----
__global__ __launch_bounds__(256) void gather_kernel(
    const float4* __restrict__ h4, const int* __restrict__ offs,
    const int* __restrict__ esrc, char* outb)
{
    int stride = gridDim.x * 256;
    for (int idx = blockIdx.x * 256 + threadIdx.x; idx < NN * 16; idx += stride) {
        int n = idx >> 4, c = idx & 15;
        int o0 = offs[n], o1 = offs[n + 1];
        float4 a = make_float4(0.f, 0.f, 0.f, 0.f);
        float4 b = make_float4(0.f, 0.f, 0.f, 0.f);
        for (int e = o0; e < o1; ++e) {
            const float4* hr = h4 + (size_t)esrc[e] * 32 + c * 2;
            float4 p0 = hr[0], p1 = hr[1];
            a.x += p0.x; a.y += p0.y; a.z += p0.z; a.w += p0.w;
            b.x += p1.x; b.y += p1.y; b.z += p1.z; b.w += p1.w;
        }
        const float4* hn = h4 + (size_t)n * 32 + c * 2;
        float4 q0 = hn[0], q1 = hn[1];
        char* slot = outb + (size_t)n * 512;
        *(uint4*)(slot + c * 16)       = pack8(a, b);
        *(uint4*)(slot + 256 + c * 16) = pack8(q0, q1);
    }
}

// ---------------- fallback atomic scatter ----------------
__global__ void scatter_kernel(const float4* __restrict__ h4,
                               const int* __restrict__ src,
                               const int* __restrict__ dst,
                               float* up, int E) {
    int tid = blockIdx.x * blockDim.x + threadIdx.x;
    int e = tid >> 5;
    if (e >= E) return;
    int c = tid & 31;
    float4 v = h4[(size_t)src[e] * 32 + c];
    float* o = up + (size_t)dst[e] * DD + c * 4;
    atomicAdd(o + 0, v.x);
    atomicAdd(o + 1, v.y);
    atomicAdd(o + 2, v.z);
    atomicAdd(o + 3, v.w);
}

// one strip iteration: current X frags XC, prefetch next strip into XN
#define NODE_BODY(XC, XN, IT) do {                                             \
    const int rbase = (strip0 + (IT)) * 16;                                    \
    const char* slot = (const char*)slots + (size_t)(rbase + m) * 512;         \
    /* prefetch next strip's X frags (clamped; overlaps GEMM1) */              \
    {                                                                          \
        int itn = ((IT) + 1 < 8) ? (IT) + 1 : 7;                               \
        const char* slotn = (const char*)slots                                 \
            + (size_t)((strip0 + itn) * 16 + m) * 512;                         \
        _Pragma("unroll")                                                      \
        for (int ks = 0; ks < 8; ++ks)                                         \
            XN[ks] = *(const bf16x8*)(slotn + ks * 64 + lk * 16);              \
    }                                                                          \
    bf16x8 xp = {};                                                            \
    if (lane < 16) {                                                           \
        int n0 = rbase + m;                                                    \
        xp[0] = (short)f2bf(signed_log(c1[n0]));                               \
        xp[1] = (short)f2bf(signed_log(c2[n0]));                               \
        xp[2] = (short)f2bf(signed_log(c3[n0]));                               \
        xp[3] = (short)f2bf(signed_log(c4[n0]));                               \
        xp[4] = (short)f2bf(signed_log(qn[n0]));                               \
    }                                                                          \
    /* GEMM1 (swapped): acc1[ct] = out^T tile ct */                            \
    f32x4 acc1[8] = {};                                                        \
    _Pragma("unroll")                                                          \
    for (int ks = 0; ks < 8; ++ks) {                                           \
        _Pragma("unroll")                                                      \
        for (int ct = 0; ct < 8; ++ct) {                                       \
            bf16x8 wf = *(const bf16x8*)(sW1 +                                 \
                (((ks * 4 + lk) * 128) + ct * 16 + m) * 8);                    \
            acc1[ct] = __builtin_amdgcn_mfma_f32_16x16x32_bf16(                \
                wf, XC[ks], acc1[ct], 0, 0, 0);                                \
        }                                                                      \
    }                                                                          \
    _Pragma("unroll")                                                          \
    for (int ct = 0; ct < 8; ++ct) {                                           \
        bf16x8 wf = *(const bf16x8*)(sW1 +                                     \
            (((32 + lk) * 128) + ct * 16 + m) * 8);                            \
        acc1[ct] = __builtin_amdgcn_mfma_f32_16x16x32_bf16(                    \
            wf, xp, acc1[ct], 0, 0, 0);                                        \
    }                                                                          \
    /* residual h (bf16, slot h-half) — issue early, used after GEMM2 */       \
    uint2 hres[8];                                                             \
    _Pragma("unroll")                                                          \
    for (int ct = 0; ct < 8; ++ct)                                             \
        hres[ct] = *(const uint2*)(slot + 256 + (ct * 16 + lk * 4) * 2);       \
    /* silu + pack -> wave-private hid LDS (swizzled, no barrier) */           \
    _Pragma("unroll")                                                          \
    for (int ct = 0; ct < 8; ++ct) {                                           \
        float4 b1v = *(const float4*)(sB + ct * 16 + lk * 4);                  \
        float v0 = acc1[ct][0] + b1v.x, v1 = acc1[ct][1] + b1v.y;              \
        float v2 = acc1[ct][2] + b1v.z, v3 = acc1[ct][3] + b1v.w;              \
        float s0 = v0 / (1.f + __expf(-v0));                                   \
        float s1 = v1 / (1.f + __expf(-v1));                                   \
        float s2 = v2 / (1.f + __expf(-v2));                                   \
        float s3 = v3 / (1.f + __expf(-v3));                                   \
        char* hb = (char*)sHid + m * 256 + ((ct * 32 + lk * 8) ^ hswz);        \
        *(uint2*)hb = make_uint2(pack2(s0, s1), pack2(s2, s3));                \
    }                                                                          \
    /* GEMM2 (swapped): B = hid^T frags from private LDS */                    \
    f32x4 acc2[8] = {};                                                        \
    _Pragma("unroll")                                                          \
    for (int ks = 0; ks < 4; ++ks) {                                           \
        bf16x8 hbf = *(const bf16x8*)((char*)sHid + m * 256 +                  \
            ((ks * 64 + lk * 16) ^ hswz));                                     \
        _Pragma("unroll")                                                      \
        for (int ct = 0; ct < 8; ++ct) {                                       \
            bf16x8 wf = *(const bf16x8*)(sW2 +                                 \
                (((ks * 4 + lk) * 128) + ct * 16 + m) * 8);                    \
            acc2[ct] = __builtin_amdgcn_mfma_f32_16x16x32_bf16(                \
                wf, hbf, acc2[ct], 0, 0, 0);                                   \
        }                                                                      \
    }                                                                          \
    /* z = out2 + b2 + h ; LN over row (in-lane + 2 shuffles) */               \
    float s = 0.f, q = 0.f;                                                    \
    _Pragma("unroll")                                                          \
    for (int ct = 0; ct < 8; ++ct) {                                           \
        float4 b2v = *(const float4*)(sB + 128 + ct * 16 + lk * 4);            \
        float z0 = acc2[ct][0] + b2v.x + bf2f((unsigned short)(hres[ct].x & 0xffff)); \
        float z1 = acc2[ct][1] + b2v.y + bf2f((unsigned short)(hres[ct].x >> 16));    \
        float z2 = acc2[ct][2] + b2v.z + bf2f((unsigned short)(hres[ct].y & 0xffff)); \
        float z3 = acc2[ct][3] + b2v.w + bf2f((unsigned short)(hres[ct].y >> 16));    \
        acc2[ct][0] = z0; acc2[ct][1] = z1; acc2[ct][2] = z2; acc2[ct][3] = z3;       \
        s += (z0 + z1) + (z2 + z3);                                            \
        q += (z0 * z0 + z1 * z1) + (z2 * z2 + z3 * z3);                        \
    }                                                                          \
    s += __shfl_xor(s, 16); q += __shfl_xor(q, 16);                            \
    s += __shfl_xor(s, 32); q += __shfl_xor(q, 32);                            \
    float mean = s * (1.f / 128.f);                                            \
    float var  = q * (1.f / 128.f) - mean * mean;                              \
    float rstd = rsqrtf(var + EPS_LN);                                         \
    float* op = out + (size_t)(rbase + m) * DD;                                \
    _Pragma("unroll")                                                          \
    for (int ct = 0; ct < 8; ++ct) {                                           \
        float4 g  = *(const float4*)(sB + 256 + ct * 16 + lk * 4);             \
        float4 bt = *(const float4*)(sB + 384 + ct * 16 + lk * 4);             \
        float4 o;                                                              \
        o.x = (acc2[ct][0] - mean) * rstd * g.x + bt.x;                        \
        o.y = (acc2[ct][1] - mean) * rstd * g.y + bt.y;                        \
        o.z = (acc2[ct][2] - mean) * rstd * g.z + bt.z;                        \
        o.w = (acc2[ct][3] - mean) * rstd * g.w + bt.w;                        \
        *(float4*)(op + ct * 16 + lk * 4) = o;                                 \
    }                                                                          \
} while (0)

// ======== fast path: zero-barrier wave-independent MLP + LN, X prefetch ====
__global__ __launch_bounds__(THREADS, 2) void node_kernel(
    const void* slots,
    const float* __restrict__ c1, const float* __restrict__ c2,
    const float* __restrict__ c3, const float* __restrict__ c4,
    const float* __restrict__ qn,
    const float* __restrict__ W1, const float* __restrict__ b1,
    const float* __restrict__ W2, const float* __restrict__ b2,
    const float* __restrict__ gamma, const float* __restrict__ beta,
    float* out)
{
    extern __shared__ char smem[];
    unsigned short* sW1 = (unsigned short*)(smem + OFF_W1);
    unsigned short* sW2 = (unsigned short*)(smem + OFF_W2);
    float* sB = (float*)(smem + OFF_B);

    const int tid  = threadIdx.x;
    const int lane = tid & 63;
    const int wv   = tid >> 6;
    const int m    = lane & 15;
    const int lk   = lane >> 4;
    unsigned short* sHid = (unsigned short*)(smem + OFF_HID + wv * 4096);
    const int hswz = (m & 3) << 5;

    // ---- stage W1 (k-permuted to slot order [up|h|phys]) ----
    for (int c = tid; c < 36 * 128; c += THREADS) {
        int kb = c >> 7, n = c & 127;
        unsigned short tmp[8] __attribute__((aligned(16)));
        #pragma unroll
        for (int j = 0; j < 8; ++j) {
            int kx = kb * 8 + j;
            int krow = (kx < 128) ? (128 + kx) : (kx < 256 ? kx - 128 : kx);
            tmp[j] = (krow < 261) ? f2bf(W1[krow * DD + n]) : (unsigned short)0;
        }
        *(uint4*)(sW1 + c * 8) = *(const uint4*)tmp;
    }
    for (int c = tid; c < 16 * 128; c += THREADS) {
        int kb = c >> 7, n = c & 127;
        unsigned short tmp[8] __attribute__((aligned(16)));
        #pragma unroll
        for (int j = 0; j < 8; ++j) tmp[j] = f2bf(W2[(kb * 8 + j) * DD + n]);
        *(uint4*)(sW2 + c * 8) = *(const uint4*)tmp;
    }
    if (tid < 128) {
        sB[tid]       = b1[tid];
        sB[128 + tid] = b2[tid];
        sB[256 + tid] = gamma[tid];
        sB[384 + tid] = beta[tid];
    }
    __syncthreads();   // the ONLY block barrier

    const int strip0 = (blockIdx.x * 8 + wv) * 8;

    // prologue: load strip 0's X frags
    bf16x8 xaA[8], xaB[8];
    {
        const char* slot0 = (const char*)slots + (size_t)(strip0 * 16 + m) * 512;
        #pragma unroll
        for (int ks = 0; ks < 8; ++ks)
            xaA[ks] = *(const bf16x8*)(slot0 + ks * 64 + lk * 16);
    }

    #pragma unroll 1
    for (int it = 0; it < 8; it += 2) {
        NODE_BODY(xaA, xaB, it);
        NODE_BODY(xaB, xaA, it + 1);
    }
}

// ============ fallback (ws too small): r4-proven LDS-weight path ============
__global__ __launch_bounds__(512) void node_kernel_fb(
    const float* __restrict__ h, const float* up,
    const float* __restrict__ c1, const float* __restrict__ c2,
    const float* __restrict__ c3, const float* __restrict__ c4,
    const float* __restrict__ qn,
    const float* __restrict__ W1, const float* __restrict__ b1,
    const float* __restrict__ W2, const float* __restrict__ b2,
    const float* __restrict__ gamma, const float* __restrict__ beta,
    float* out)
{
    extern __shared__ char smem[];
    unsigned short* sW1 = (unsigned short*)(smem + FB_OFF_W1);
    unsigned short* sW2 = (unsigned short*)(smem + FB_OFF_W2);
    unsigned short* sX  = (unsigned short*)(smem + FB_OFF_X);
    unsigned short* sH  = (unsigned short*)(smem + FB_OFF_H);
    float2* red = (float2*)(smem + FB_OFF_RED);

    const int tid = threadIdx.x;

    for (int c = tid; c < 36 * 128; c += 512) {
        int kb = c >> 7, n = c & 127;
        unsigned short tmp[8] __attribute__((aligned(16)));
        #pragma unroll
        for (int j = 0; j < 8; ++j) {
            int k = kb * 8 + j;
            tmp[j] = (k < 261) ? f2bf(W1[k * DD + n]) : (unsigned short)0;
        }
        *(uint4*)(sW1 + c * 8) = *(const uint4*)tmp;
    }
    for (int c = tid; c < 16 * 128; c += 512) {
        int kb = c >> 7, n = c & 127;
        unsigned short tmp[8] __attribute__((aligned(16)));
        #pragma unroll
        for (int j = 0; j < 8; ++j) tmp[j] = f2bf(W2[(kb * 8 + j) * DD + n]);
        *(uint4*)(sW2 + c * 8) = *(const uint4*)tmp;
    }
    if (tid < 192) {
        int kb = 33 + (tid >> 6), row = tid & 63;
        stx64(sX, kb, row, make_uint4(0u, 0u, 0u, 0u));
    }

    const int lane = tid & 63;
    const int w    = tid >> 6;
    const int wm   = w >> 2;
    const int wn   = w & 3;
    const int l15  = lane & 15;
    const int lk   = lane >> 4;
    const int col0 = wn * 32 + l15;
    const int col1 = col0 + 16;

    const float b1v[2] = {b1[col0], b1[col1]};
    const float b2v[2] = {b2[col0], b2[col1]};
    const float gv[2]  = {gamma[col0], gamma[col1]};
    const float bv[2]  = {beta[col0], beta[col1]};

    const bf16x8* W1f = (const bf16x8*)sW1;
    const bf16x8* Hf  = (const bf16x8*)sH;
    const bf16x8* W2f = (const bf16x8*)sW2;

    const int k0 = tid & 15;
    const int r0 = tid >> 4;

    float4 h0a, h0b, h1a, h1b, v0a, v0b, v1a, v1b;
    float pc1 = 0.f, pc2 = 0.f, pc3 = 0.f, pc4 = 0.f, pc5 = 0.f;

    {
        int base = blockIdx.x * 16 * 64;
        const float* hp = h + (size_t)(base + r0) * DD + k0 * 8;
        h0a = *(const float4*)hp;             h0b = *(const float4*)(hp + 4);
        h1a = *(const float4*)(hp + 32 * DD); h1b = *(const float4*)(hp + 32 * DD + 4);
        const float* uf = up + (size_t)(base + r0) * DD + k0 * 8;
        v0a = *(const float4*)uf;             v0b = *(const float4*)(uf + 4);
        v1a = *(const float4*)(uf + 32 * DD); v1b = *(const float4*)(uf + 32 * DD + 4);
        if (tid < 64) {
            int n0 = base + tid;
            pc1 = c1[n0]; pc2 = c2[n0]; pc3 = c3[n0]; pc4 = c4[n0]; pc5 = qn[n0];
        }
    }
    __syncthreads();

    for (int tt = 0; tt < 16; ++tt) {
        const int base = (blockIdx.x * 16 + tt) * 64;

        stx64(sX, k0, r0,           pack8(h0a, h0b));
        stx64(sX, k0, r0 + 32,      pack8(h1a, h1b));
        stx64(sX, 16 + k0, r0,      pack8(v0a, v0b));
        stx64(sX, 16 + k0, r0 + 32, pack8(v1a, v1b));
        if (tid < 64) {
            uint4 pv = make_uint4(pack2(signed_log(pc1), signed_log(pc2)),
                                  pack2(signed_log(pc3), signed_log(pc4)),
                                  pack2(signed_log(pc5), 0.f), 0u);
            stx64(sX, 32, tid, pv);
        }
        if (tt + 1 < 16) {
            int bn = base + 64;
            const float* hp = h + (size_t)(bn + r0) * DD + k0 * 8;
            h0a = *(const float4*)hp;             h0b = *(const float4*)(hp + 4);
            h1a = *(const float4*)(hp + 32 * DD); h1b = *(const float4*)(hp + 32 * DD + 4);
            const float* uf = up + (size_t)(bn + r0) * DD + k0 * 8;
            v0a = *(const float4*)uf;             v0b = *(const float4*)(uf + 4);
            v1a = *(const float4*)(uf + 32 * DD); v1b = *(const float4*)(uf + 32 * DD + 4);
            if (tid < 64) {
                int n0 = bn + tid;
                pc1 = c1[n0]; pc2 = c2[n0]; pc3 = c3[n0]; pc4 = c4[n0]; pc5 = qn[n0];
            }
        }
        __syncthreads();

        f32x4 acc[2][2] = {};
        #pragma unroll
        for (int ks = 0; ks < 9; ++ks) {
            int kb = ks * 4 + lk;
            bf16x8 a0  = ldx64(sX, kb, wm * 32 + l15);
            bf16x8 a1  = ldx64(sX, kb, wm * 32 + 16 + l15);
            bf16x8 bb0 = W1f[kb * 128 + col0];
            bf16x8 bb1 = W1f[kb * 128 + col1];
            acc[0][0] = __builtin_amdgcn_mfma_f32_16x16x32_bf16(a0, bb0, acc[0][0], 0, 0, 0);
            acc[0][1] = __builtin_amdgcn_mfma_f32_16x16x32_bf16(a0, bb1, acc[0][1], 0, 0, 0);
            acc[1][0] = __builtin_amdgcn_mfma_f32_16x16x32_bf16(a1, bb0, acc[1][0], 0, 0, 0);
            acc[1][1] = __builtin_amdgcn_mfma_f32_16x16x32_bf16(a1, bb1, acc[1][1], 0, 0, 0);
        }
        #pragma unroll
        for (int fm = 0; fm < 2; ++fm) {
            int row = wm * 32 + fm * 16 + lk * 4;
            #pragma unroll
            for (int fn = 0; fn < 2; ++fn) {
                int col = wn * 32 + fn * 16 + l15;
                int kbh = col >> 3, ko = col & 7;
                #pragma unroll
                for (int r = 0; r < 4; ++r) {
                    float v = acc[fm][fn][r] + b1v[fn];
                    float sg = 1.f / (1.f + __expf(-v));
                    sH[(kbh * 64 + row + r) * 8 + ko] = f2bf(v * sg);
                }
            }
        }
        __syncthreads();

        f32x4 acc2[2][2] = {};
        #pragma unroll
        for (int ks = 0; ks < 4; ++ks) {
            int kb = ks * 4 + lk;
            bf16x8 a0  = Hf[kb * 64 + wm * 32 + l15];
            bf16x8 a1  = Hf[kb * 64 + wm * 32 + 16 + l15];
            bf16x8 bb0 = W2f[kb * 128 + col0];
            bf16x8 bb1 = W2f[kb * 128 + col1];
            acc2[0][0] = __builtin_amdgcn_mfma_f32_16x16x32_bf16(a0, bb0, acc2[0][0], 0, 0, 0);
            acc2[0][1] = __builtin_amdgcn_mfma_f32_16x16x32_bf16(a0, bb1, acc2[0][1], 0, 0, 0);
            acc2[1][0] = __builtin_amdgcn_mfma_f32_16x16x32_bf16(a1, bb0, acc2[1][0], 0, 0, 0);
            acc2[1][1] = __builtin_amdgcn_mfma_f32_16x16x32_bf16(a1, bb1, acc2[1][1], 0, 0, 0);
        }

        float rs1[2][4], rs2[2][4];
        #pragma unroll
        for (int fm = 0; fm < 2; ++fm) {
            #pragma unroll
            for (int r = 0; r < 4; ++r) {
                size_t rowg = (size_t)(base + wm * 32 + fm * 16 + lk * 4 + r) * DD;
                float z0 = acc2[fm][0][r] + b2v[0] + h[rowg + col0];
                float z1 = acc2[fm][1][r] + b2v[1] + h[rowg + col1];
                acc2[fm][0][r] = z0; acc2[fm][1][r] = z1;
                float s = z0 + z1, q = z0 * z0 + z1 * z1;
                #pragma unroll
                for (int off = 1; off < 16; off <<= 1) {
                    s += __shfl_xor(s, off);
                    q += __shfl_xor(q, off);
                }
                rs1[fm][r] = s; rs2[fm][r] = q;
            }
        }
        if (l15 == 0) {
            #pragma unroll
            for (int fm = 0; fm < 2; ++fm)
                #pragma unroll
                for (int r = 0; r < 4; ++r)
                    red[wn * 64 + wm * 32 + fm * 16 + lk * 4 + r] =
                        make_float2(rs1[fm][r], rs2[fm][r]);
        }
        __syncthreads();

        #pragma unroll
        for (int fm = 0; fm < 2; ++fm) {
            #pragma unroll
            for (int r = 0; r < 4; ++r) {
                int rloc = wm * 32 + fm * 16 + lk * 4 + r;
                float2 t0 = red[rloc], t1 = red[64 + rloc],
                       t2 = red[128 + rloc], t3 = red[192 + rloc];
                float S = t0.x + t1.x + t2.x + t3.x;
                float Q = t0.y + t1.y + t2.y + t3.y;
                float mean = S * (1.f / 128.f);
                float var  = Q * (1.f / 128.f) - mean * mean;
                float rstd = rsqrtf(var + EPS_LN);
                size_t rowg = (size_t)(base + rloc) * DD;
                out[rowg + col0] = (acc2[fm][0][r] - mean) * rstd * gv[0] + bv[0];
                out[rowg + col1] = (acc2[fm][1][r] - mean) * rstd * gv[1] + bv[1];
            }
        }
    }
}

extern "C" void kernel_launch(void* const* d_in, const int* in_sizes, int n_in,
                              void* d_out, int out_size, void* d_ws, size_t ws_size,
                              hipStream_t stream) {
    const float* h     = (const float*)d_in[0];
    const float* c1    = (const float*)d_in[1];
    const float* c2    = (const float*)d_in[2];
    const float* c3    = (const float*)d_in[3];
    const float* c4    = (const float*)d_in[4];
    const float* qn    = (const float*)d_in[5];
    const int*   src   = (const int*)d_in[6];
    const int*   dst   = (const int*)d_in[7];
    const float* W1    = (const float*)d_in[8];
    const float* b1    = (const float*)d_in[9];
    const float* W2    = (const float*)d_in[10];
    const float* b2    = (const float*)d_in[11];
    const float* gamma = (const float*)d_in[12];
    const float* beta  = (const float*)d_in[13];
    float* out = (float*)d_out;
    int E = in_sizes[6];
    size_t ws_needed = (size_t)WS_ESRC + (size_t)E * 4;

    if (ws_size >= ws_needed) {
        char* ws = (char*)d_ws;
        int* offs   = (int*)(ws + WS_OFFS);
        int* cursor = (int*)(ws + WS_CURSOR);
        int* bsum   = (int*)(ws + WS_BSUM);
        int* esrc   = (int*)(ws + WS_ESRC);

        hipMemsetAsync(offs, 0, (size_t)NN * sizeof(int), stream);
        int eb = (E + 255) / 256;
        hist_kernel<<<eb, 256, 0, stream>>>(dst, offs, E);
        scan_local<<<NN / 256, 256, 0, stream>>>(offs, bsum);
        scan_bsum<<<1, 1024, 0, stream>>>(bsum);
        scan_fixup<<<NN / 256, 256, 0, stream>>>(offs, bsum, cursor, E);
        fill_kernel<<<eb, 256, 0, stream>>>(src, dst, cursor, esrc, E);

        gather_kernel<<<2048, 256, 0, stream>>>((const float4*)h, offs, esrc, (char*)d_out);

        hipFuncSetAttribute(reinterpret_cast<const void*>(&node_kernel),
                            hipFuncAttributeMaxDynamicSharedMemorySize, SMEM_TOT);
        node_kernel<<<NBLOCKS, THREADS, SMEM_TOT, stream>>>(
            d_out, c1, c2, c3, c4, qn,
            W1, b1, W2, b2, gamma, beta, out);
    } else {
        // fallback: atomic scatter into d_out (fp32 upstream), LDS-weight kernel
        hipMemsetAsync(d_out, 0, (size_t)NN * DD * sizeof(float), stream);
        int sthreads = E * 32;
        int sblocks = (sthreads + 255) / 256;
        scatter_kernel<<<sblocks, 256, 0, stream>>>((const float4*)h, src, dst, out, E);
        hipFuncSetAttribute(reinterpret_cast<const void*>(&node_kernel_fb),
                            hipFuncAttributeMaxDynamicSharedMemorySize, FB_SMEM_TOT);
        node_kernel_fb<<<256, 512, FB_SMEM_TOT, stream>>>(
            h, out, c1, c2, c3, c4, qn,
            W1, b1, W2, b2, gamma, beta, out);
    }
}

// Round 15
// 226.340 us; speedup vs baseline: 1.5605x; 1.1539x over previous
//
#include <hip/hip_runtime.h>
#include <math.h>

#define NN 262144
#define DD 128
#define EPS_SL 1e-8f
#define EPS_LN 1e-5f
#define THREADS 512
#define TILE_M 64
#define NBLOCKS 256
#define NTILES (NN / TILE_M)          // 4096
#define TPB (NTILES / NBLOCKS)        // 16

typedef __attribute__((ext_vector_type(8))) short bf16x8;
typedef __attribute__((ext_vector_type(4))) float f32x4;

// LDS layout (bytes). Subtiled MFMA-native [kb][row][8] bf16; X XOR-swizzled.
#define OFF_W1 0                       // [36][128][8] bf16 = 73728 B  (K=288 pad)
#define OFF_W2 73728                   // [16][128][8] bf16 = 32768 B
#define OFF_X  106496                  // [36][64][8]  bf16 = 36864 B
#define OFF_H  143360                  // [16][64][8]  bf16 = 16384 B
#define OFF_RED 159744                 // 256 float2   =  2048 B
#define SMEM_TOT 161792

// d_ws layout (CSR build)
#define WS_OFFS   0                    // (NN+1) int
#define WS_CURSOR 1048832              // NN int
#define WS_BSUM   2097408              // 1024 int
#define WS_ESRC   2101504              // E int

__device__ inline unsigned short f2bf(float f) {
    union { float f; unsigned int i; } v; v.f = f;
    unsigned int r = v.i + 0x7fffu + ((v.i >> 16) & 1u);
    return (unsigned short)(r >> 16);
}
__device__ inline unsigned int pack2(float a, float b) {
    return (unsigned int)f2bf(a) | ((unsigned int)f2bf(b) << 16);
}
__device__ inline uint4 pack8(float4 a, float4 b) {
    return make_uint4(pack2(a.x, a.y), pack2(a.z, a.w),
                      pack2(b.x, b.y), pack2(b.z, b.w));
}
__device__ inline float signed_log(float x) {
    float l = __logf(fabsf(x) + EPS_SL);
    return (x > 0.f) ? l : ((x < 0.f) ? -l : 0.f);
}
// swizzled X store/load: unit index (kb*64+row) ^ (kb&7)
__device__ inline void stx(unsigned short* sX, int kb, int row, uint4 v) {
    *(uint4*)(sX + (((kb * 64 + row) ^ (kb & 7)) * 8)) = v;
}
__device__ inline bf16x8 ldx(const unsigned short* sX, int kb, int row) {
    return *(const bf16x8*)(sX + (((kb * 64 + row) ^ (kb & 7)) * 8));
}

// LDS-only block barrier (no vmcnt drain; r10-proven)
__device__ inline void block_sync_lds() {
    __builtin_amdgcn_sched_barrier(0);
    asm volatile("s_waitcnt lgkmcnt(0)" ::: "memory");
    __builtin_amdgcn_s_barrier();
    __builtin_amdgcn_sched_barrier(0);
}

// ---------------- CSR build ----------------
__global__ void hist_kernel(const int* __restrict__ dst, int* counts, int E) {
    int t = blockIdx.x * blockDim.x + threadIdx.x;
    int e = t * 2;
    if (e + 1 < E) {
        int2 d = *(const int2*)(dst + e);
        atomicAdd(&counts[d.x], 1);
        atomicAdd(&counts[d.y], 1);
    } else if (e < E) {
        atomicAdd(&counts[dst[e]], 1);
    }
}

__global__ void scan_local(int* offs, int* bsum) {
    __shared__ int tmp[256];
    int t = threadIdx.x, i = blockIdx.x * 256 + t;
    int own = offs[i];
    tmp[t] = own;
    __syncthreads();
    for (int off = 1; off < 256; off <<= 1) {
        int v = (t >= off) ? tmp[t - off] : 0;
        __syncthreads();
        tmp[t] += v;
        __syncthreads();
    }
    offs[i] = tmp[t] - own;
    if (t == 255) bsum[blockIdx.x] = tmp[255];
}

// merged: each block computes its own prefix over raw bsum (1024 entries),
// then applies it — removes the separate scan_bsum dispatch.
__global__ void scan_fixup(int* offs, const int* __restrict__ bsum, int* cursor, int E) {
    __shared__ int wsum[4];
    const int b = blockIdx.x;          // 0..1023
    const int t = threadIdx.x;         // 0..255
    int acc = 0;
    #pragma unroll
    for (int j = 0; j < 4; ++j) {
        int idx = j * 256 + t;
        acc += (idx < b) ? bsum[idx] : 0;
    }
    #pragma unroll
    for (int off = 1; off < 64; off <<= 1) acc += __shfl_xor(acc, off);
    if ((t & 63) == 0) wsum[t >> 6] = acc;
    __syncthreads();
    int prefix = wsum[0] + wsum[1] + wsum[2] + wsum[3];
    int i = b * 256 + t;
    int v = offs[i] + prefix;
    offs[i] = v;
    cursor[i] = v;
    if (i == 0) offs[NN] = E;
}

__global__ void fill_kernel(const int* __restrict__ src, const int* __restrict__ dst,
                            int* cursor, int* esrc, int E) {
    int t = blockIdx.x * blockDim.x + threadIdx.x;
    int e = t * 2;
    if (e + 1 < E) {
        int2 s = *(const int2*)(src + e);
        int2 d = *(const int2*)(dst + e);
        int p0 = atomicAdd(&cursor[d.x], 1);
        esrc[p0] = s.x;
        int p1 = atomicAdd(&cursor[d.y], 1);
        esrc[p1] = s.y;
    } else if (e < E) {
        int p = atomicAdd(&cursor[dst[e]], 1);
        esrc[p] = src[e];
    }
}

// ---------------- CSR gather -> upstream bf16 (one row per 512B out slot) ----
__global__ __launch_bounds__(256) void gather_kernel(
    const float4* __restrict__ h4, const int* __restrict__ offs,
    const int* __restrict__ esrc, char* outb)
{
    int stride = gridDim.x * 256;
    for (int idx = blockIdx.x * 256 + threadIdx.x; idx < NN * 16; idx += stride) {
        int n = idx >> 4, c = idx & 15;
        int o0 = offs[n], o1 = offs[n + 1];
        float4 a = make_float4(0.f, 0.f, 0.f, 0.f);
        float4 b = make_float4(0.f, 0.f, 0.f, 0.f);
        for (int e = o0; e < o1; ++e) {
            const float4* hr = h4 + (size_t)esrc[e] * 32 + c * 2;
            float4 p0 = hr[0], p1 = hr[1];
            a.x += p0.x; a.y += p0.y; a.z += p0.z; a.w += p0.w;
            b.x += p1.x; b.y += p1.y; b.z += p1.z; b.w += p1.w;
        }
        *(uint4*)(outb + (size_t)n * 512 + c * 16) = pack8(a, b);
    }
}

// ---------------- fallback atomic scatter ----------------
__global__ void scatter_kernel(const float4* __restrict__ h4,
                               const int* __restrict__ src,
                               const int* __restrict__ dst,
                               float* up, int E) {
    int tid = blockIdx.x * blockDim.x + threadIdx.x;
    int e = tid >> 5;
    if (e >= E) return;
    int c = tid & 31;
    float4 v = h4[(size_t)src[e] * 32 + c];
    float* o = up + (size_t)dst[e] * DD + c * 4;
    atomicAdd(o + 0, v.x);
    atomicAdd(o + 1, v.y);
    atomicAdd(o + 2, v.z);
    atomicAdd(o + 3, v.w);
}

// ---------------- pipelined MFMA node MLP + LayerNorm (r10 champion) --------
// GATHER=1: up = bf16 rows at (char*)out + n*512 (written by gather_kernel)
// GATHER=0: up = fp32 rows in out (written by scatter_kernel)
// Aliasing safe: all slot reads of tile t are consumed at that tile's staging
// stx before B1; the aliased out-stores to those bytes happen after B2.
template <int GATHER>
__global__ __launch_bounds__(THREADS) void node_kernel(
    const float* __restrict__ h, const void* up,
    const float* __restrict__ c1, const float* __restrict__ c2,
    const float* __restrict__ c3, const float* __restrict__ c4,
    const float* __restrict__ qn,
    const float* __restrict__ W1, const float* __restrict__ b1,
    const float* __restrict__ W2, const float* __restrict__ b2,
    const float* __restrict__ gamma, const float* __restrict__ beta,
    float* out)
{
    extern __shared__ char smem[];
    unsigned short* sW1 = (unsigned short*)(smem + OFF_W1);
    unsigned short* sW2 = (unsigned short*)(smem + OFF_W2);
    unsigned short* sX  = (unsigned short*)(smem + OFF_X);
    unsigned short* sH  = (unsigned short*)(smem + OFF_H);
    float2* red = (float2*)(smem + OFF_RED);

    const int tid = threadIdx.x;

    // ---- stage transposed bf16 weights once per block ----
    for (int c = tid; c < 36 * 128; c += THREADS) {
        int kb = c >> 7, n = c & 127;
        unsigned short tmp[8] __attribute__((aligned(16)));
        #pragma unroll
        for (int j = 0; j < 8; ++j) {
            int k = kb * 8 + j;
            tmp[j] = (k < 261) ? f2bf(W1[k * DD + n]) : (unsigned short)0;
        }
        *(uint4*)(sW1 + c * 8) = *(const uint4*)tmp;
    }
    for (int c = tid; c < 16 * 128; c += THREADS) {
        int kb = c >> 7, n = c & 127;
        unsigned short tmp[8] __attribute__((aligned(16)));
        #pragma unroll
        for (int j = 0; j < 8; ++j) tmp[j] = f2bf(W2[(kb * 8 + j) * DD + n]);
        *(uint4*)(sW2 + c * 8) = *(const uint4*)tmp;
    }
    // zero pad rows kb 33..35 once (never overwritten)
    if (tid < 192) {
        int kb = 33 + (tid >> 6), row = tid & 63;
        stx(sX, kb, row, make_uint4(0u, 0u, 0u, 0u));
    }

    const int lane = tid & 63;
    const int w    = tid >> 6;
    const int wm   = w >> 2;
    const int wn   = w & 3;
    const int l15  = lane & 15;
    const int lk   = lane >> 4;
    const int col0 = wn * 32 + l15;
    const int col1 = col0 + 16;

    const float b1v[2] = {b1[col0], b1[col1]};
    const float b2v[2] = {b2[col0], b2[col1]};
    const float gv[2]  = {gamma[col0], gamma[col1]};
    const float bv[2]  = {beta[col0], beta[col1]};

    const bf16x8* W1f = (const bf16x8*)sW1;
    const bf16x8* Hf  = (const bf16x8*)sH;
    const bf16x8* W2f = (const bf16x8*)sW2;

    // chunk coords (loop-invariant): thread owns (k0, r0) and (k0, r0+32)
    const int k0 = tid & 15;
    const int r0 = tid >> 4;          // 0..31

    // prefetch registers
    float4 h0a, h0b, h1a, h1b;
    uint4  u0, u1;                    // GATHER=1
    float4 v0a, v0b, v1a, v1b;        // GATHER=0
    float pc1 = 0.f, pc2 = 0.f, pc3 = 0.f, pc4 = 0.f, pc5 = 0.f;

    // ---- prologue prefetch: tile 0 ----
    {
        int base = blockIdx.x * TPB * TILE_M;
        const float* hp = h + (size_t)(base + r0) * DD + k0 * 8;
        h0a = *(const float4*)hp;       h0b = *(const float4*)(hp + 4);
        h1a = *(const float4*)(hp + 32 * DD); h1b = *(const float4*)(hp + 32 * DD + 4);
        if (GATHER) {
            const char* ub = (const char*)up;
            u0 = *(const uint4*)(ub + (size_t)(base + r0) * 512 + k0 * 16);
            u1 = *(const uint4*)(ub + (size_t)(base + r0 + 32) * 512 + k0 * 16);
        } else {
            const float* uf = (const float*)up + (size_t)(base + r0) * DD + k0 * 8;
            v0a = *(const float4*)uf;       v0b = *(const float4*)(uf + 4);
            v1a = *(const float4*)(uf + 32 * DD); v1b = *(const float4*)(uf + 32 * DD + 4);
        }
        if (tid < 64) {
            int n0 = base + tid;
            pc1 = c1[n0]; pc2 = c2[n0]; pc3 = c3[n0]; pc4 = c4[n0]; pc5 = qn[n0];
        }
    }
    __syncthreads();

    for (int tt = 0; tt < TPB; ++tt) {
        const int base = (blockIdx.x * TPB + tt) * TILE_M;

        // ---- write prefetched regs -> sX ----
        stx(sX, k0, r0,      pack8(h0a, h0b));
        stx(sX, k0, r0 + 32, pack8(h1a, h1b));
        if (GATHER) {
            stx(sX, 16 + k0, r0,      u0);
            stx(sX, 16 + k0, r0 + 32, u1);
        } else {
            stx(sX, 16 + k0, r0,      pack8(v0a, v0b));
            stx(sX, 16 + k0, r0 + 32, pack8(v1a, v1b));
        }
        if (tid < 64) {
            uint4 pv = make_uint4(pack2(signed_log(pc1), signed_log(pc2)),
                                  pack2(signed_log(pc3), signed_log(pc4)),
                                  pack2(signed_log(pc5), 0.f), 0u);
            stx(sX, 32, tid, pv);
        }

        // ---- issue prefetch for next tile (overlaps GEMM + epilogue) ----
        if (tt + 1 < TPB) {
            int bn = base + TILE_M;
            const float* hp = h + (size_t)(bn + r0) * DD + k0 * 8;
            h0a = *(const float4*)hp;       h0b = *(const float4*)(hp + 4);
            h1a = *(const float4*)(hp + 32 * DD); h1b = *(const float4*)(hp + 32 * DD + 4);
            if (GATHER) {
                const char* ub = (const char*)up;
                u0 = *(const uint4*)(ub + (size_t)(bn + r0) * 512 + k0 * 16);
                u1 = *(const uint4*)(ub + (size_t)(bn + r0 + 32) * 512 + k0 * 16);
            } else {
                const float* uf = (const float*)up + (size_t)(bn + r0) * DD + k0 * 8;
                v0a = *(const float4*)uf;       v0b = *(const float4*)(uf + 4);
                v1a = *(const float4*)(uf + 32 * DD); v1b = *(const float4*)(uf + 32 * DD + 4);
            }
            if (tid < 64) {
                int n0 = bn + tid;
                pc1 = c1[n0]; pc2 = c2[n0]; pc3 = c3[n0]; pc4 = c4[n0]; pc5 = qn[n0];
            }
        }
        block_sync_lds();   // B1: sX ready

        // ---- GEMM1: (64x288) @ (288x128) ----
        f32x4 acc[2][2] = {};
        #pragma unroll
        for (int ks = 0; ks < 9; ++ks) {
            int kb = ks * 4 + lk;
            bf16x8 a0  = ldx(sX, kb, wm * 32 + l15);
            bf16x8 a1  = ldx(sX, kb, wm * 32 + 16 + l15);
            bf16x8 bb0 = W1f[kb * 128 + col0];
            bf16x8 bb1 = W1f[kb * 128 + col1];
            acc[0][0] = __builtin_amdgcn_mfma_f32_16x16x32_bf16(a0, bb0, acc[0][0], 0, 0, 0);
            acc[0][1] = __builtin_amdgcn_mfma_f32_16x16x32_bf16(a0, bb1, acc[0][1], 0, 0, 0);
            acc[1][0] = __builtin_amdgcn_mfma_f32_16x16x32_bf16(a1, bb0, acc[1][0], 0, 0, 0);
            acc[1][1] = __builtin_amdgcn_mfma_f32_16x16x32_bf16(a1, bb1, acc[1][1], 0, 0, 0);
        }
        // silu -> hid tile
        #pragma unroll
        for (int fm = 0; fm < 2; ++fm) {
            int row = wm * 32 + fm * 16 + lk * 4;
            #pragma unroll
            for (int fn = 0; fn < 2; ++fn) {
                int col = wn * 32 + fn * 16 + l15;
                int kbh = col >> 3, ko = col & 7;
                #pragma unroll
                for (int r = 0; r < 4; ++r) {
                    float v = acc[fm][fn][r] + b1v[fn];
                    float sg = 1.f / (1.f + __expf(-v));
                    sH[(kbh * 64 + row + r) * 8 + ko] = f2bf(v * sg);
                }
            }
        }
        block_sync_lds();   // B2: sH ready

        // ---- GEMM2: (64x128) @ (128x128) ----
        f32x4 acc2[2][2] = {};
        #pragma unroll
        for (int ks = 0; ks < 4; ++ks) {
            int kb = ks * 4 + lk;
            bf16x8 a0  = Hf[kb * 64 + wm * 32 + l15];
            bf16x8 a1  = Hf[kb * 64 + wm * 32 + 16 + l15];
            bf16x8 bb0 = W2f[kb * 128 + col0];
            bf16x8 bb1 = W2f[kb * 128 + col1];
            acc2[0][0] = __builtin_amdgcn_mfma_f32_16x16x32_bf16(a0, bb0, acc2[0][0], 0, 0, 0);
            acc2[0][1] = __builtin_amdgcn_mfma_f32_16x16x32_bf16(a0, bb1, acc2[0][1], 0, 0, 0);
            acc2[1][0] = __builtin_amdgcn_mfma_f32_16x16x32_bf16(a1, bb0, acc2[1][0], 0, 0, 0);
            acc2[1][1] = __builtin_amdgcn_mfma_f32_16x16x32_bf16(a1, bb1, acc2[1][1], 0, 0, 0);
        }

        // ---- residual + LN partials ----
        float rs1[2][4], rs2[2][4];
        #pragma unroll
        for (int fm = 0; fm < 2; ++fm) {
            #pragma unroll
            for (int r = 0; r < 4; ++r) {
                size_t rowg = (size_t)(base + wm * 32 + fm * 16 + lk * 4 + r) * DD;
                float z0 = acc2[fm][0][r] + b2v[0] + h[rowg + col0];
                float z1 = acc2[fm][1][r] + b2v[1] + h[rowg + col1];
                acc2[fm][0][r] = z0; acc2[fm][1][r] = z1;
                float s = z0 + z1, q = z0 * z0 + z1 * z1;
                #pragma unroll
                for (int off = 1; off < 16; off <<= 1) {
                    s += __shfl_xor(s, off);
                    q += __shfl_xor(q, off);
                }
                rs1[fm][r] = s; rs2[fm][r] = q;
            }
        }
        if (l15 == 0) {
            #pragma unroll
            for (int fm = 0; fm < 2; ++fm)
                #pragma unroll
                for (int r = 0; r < 4; ++r)
                    red[wn * 64 + wm * 32 + fm * 16 + lk * 4 + r] =
                        make_float2(rs1[fm][r], rs2[fm][r]);
        }
        block_sync_lds();   // B3: red ready

        #pragma unroll
        for (int fm = 0; fm < 2; ++fm) {
            #pragma unroll
            for (int r = 0; r < 4; ++r) {
                int rloc = wm * 32 + fm * 16 + lk * 4 + r;
                float2 t0 = red[rloc], t1 = red[64 + rloc],
                       t2 = red[128 + rloc], t3 = red[192 + rloc];
                float S = t0.x + t1.x + t2.x + t3.x;
                float Q = t0.y + t1.y + t2.y + t3.y;
                float mean = S * (1.f / 128.f);
                float var  = Q * (1.f / 128.f) - mean * mean;
                float rstd = rsqrtf(var + EPS_LN);
                size_t rowg = (size_t)(base + rloc) * DD;
                out[rowg + col0] = (acc2[fm][0][r] - mean) * rstd * gv[0] + bv[0];
                out[rowg + col1] = (acc2[fm][1][r] - mean) * rstd * gv[1] + bv[1];
            }
        }
        // loop back: sX rewrite is 2+ barriers after last sX read -> safe
    }
}

extern "C" void kernel_launch(void* const* d_in, const int* in_sizes, int n_in,
                              void* d_out, int out_size, void* d_ws, size_t ws_size,
                              hipStream_t stream) {
    const float* h     = (const float*)d_in[0];
    const float* c1    = (const float*)d_in[1];
    const float* c2    = (const float*)d_in[2];
    const float* c3    = (const float*)d_in[3];
    const float* c4    = (const float*)d_in[4];
    const float* qn    = (const float*)d_in[5];
    const int*   src   = (const int*)d_in[6];
    const int*   dst   = (const int*)d_in[7];
    const float* W1    = (const float*)d_in[8];
    const float* b1    = (const float*)d_in[9];
    const float* W2    = (const float*)d_in[10];
    const float* b2    = (const float*)d_in[11];
    const float* gamma = (const float*)d_in[12];
    const float* beta  = (const float*)d_in[13];
    float* out = (float*)d_out;
    int E = in_sizes[6];
    size_t ws_needed = (size_t)WS_ESRC + (size_t)E * 4;

    if (ws_size >= ws_needed) {
        char* ws = (char*)d_ws;
        int* offs   = (int*)(ws + WS_OFFS);
        int* cursor = (int*)(ws + WS_CURSOR);
        int* bsum   = (int*)(ws + WS_BSUM);
        int* esrc   = (int*)(ws + WS_ESRC);

        hipMemsetAsync(offs, 0, (size_t)NN * sizeof(int), stream);
        int eb2 = (E / 2 + 255) / 256;
        hist_kernel<<<eb2, 256, 0, stream>>>(dst, offs, E);
        scan_local<<<NN / 256, 256, 0, stream>>>(offs, bsum);
        scan_fixup<<<NN / 256, 256, 0, stream>>>(offs, bsum, cursor, E);
        fill_kernel<<<eb2, 256, 0, stream>>>(src, dst, cursor, esrc, E);

        gather_kernel<<<2048, 256, 0, stream>>>((const float4*)h, offs, esrc, (char*)d_out);

        hipFuncSetAttribute(reinterpret_cast<const void*>(&node_kernel<1>),
                            hipFuncAttributeMaxDynamicSharedMemorySize, SMEM_TOT);
        node_kernel<1><<<NBLOCKS, THREADS, SMEM_TOT, stream>>>(
            h, d_out, c1, c2, c3, c4, qn,
            W1, b1, W2, b2, gamma, beta, out);
    } else {
        // fallback: atomic scatter into d_out (fp32 upstream)
        hipMemsetAsync(d_out, 0, (size_t)NN * DD * sizeof(float), stream);
        int sthreads = E * 32;
        int sblocks = (sthreads + 255) / 256;
        scatter_kernel<<<sblocks, 256, 0, stream>>>((const float4*)h, src, dst, out, E);
        hipFuncSetAttribute(reinterpret_cast<const void*>(&node_kernel<0>),
                            hipFuncAttributeMaxDynamicSharedMemorySize, SMEM_TOT);
        node_kernel<0><<<NBLOCKS, THREADS, SMEM_TOT, stream>>>(
            h, d_out, c1, c2, c3, c4, qn,
            W1, b1, W2, b2, gamma, beta, out);
    }
}